// Round 12
// baseline (138.663 us; speedup 1.0000x reference)
//
#include <hip/hip_runtime.h>
#include <hip/hip_bf16.h>

typedef __attribute__((ext_vector_type(8))) short short8;
typedef __attribute__((ext_vector_type(4))) float f32x4;
typedef __attribute__((ext_vector_type(16))) float f32x16;
typedef __attribute__((ext_vector_type(4))) unsigned uint4v;

#define MFMA16(a, b, c) __builtin_amdgcn_mfma_f32_16x16x32_bf16((a), (b), (c), 0, 0, 0)
#define MFMA32(a, b, c) __builtin_amdgcn_mfma_f32_32x32x16_bf16((a), (b), (c), 0, 0, 0)

// dims
#define NB 2
#define NSEQ 4096
#define DMODEL 512
#define NH 8
#define HD 64
#define CSTRIDE (NB * NSEQ * DMODEL)  // 4194304

#define QSCALE 0.18033688011112042f  // 0.125 * log2(e), folded into Q prepass

static __device__ __forceinline__ unsigned short f2bf(float f) {
    unsigned u = __builtin_bit_cast(unsigned, f);
    u += 0x7fffu + ((u >> 16) & 1u);
    return (unsigned short)(u >> 16);
}

static __device__ __forceinline__ short8 cvt8(float4 a, float4 b) {
    short8 r;
    r[0] = (short)f2bf(a.x); r[1] = (short)f2bf(a.y);
    r[2] = (short)f2bf(a.z); r[3] = (short)f2bf(a.w);
    r[4] = (short)f2bf(b.x); r[5] = (short)f2bf(b.y);
    r[6] = (short)f2bf(b.z); r[7] = (short)f2bf(b.w);
    return r;
}

static __device__ __forceinline__ unsigned cvt_pk_bf16(float lo, float hi) {
    unsigned r;
    asm("v_cvt_pk_bf16_f32 %0, %1, %2" : "=v"(r) : "v"(lo), "v"(hi));
    return r;
}

// ---------------------------------------------------------------------------
// Prepass 1: Q,K fp32 [b,n,h*64+d] -> bf16 [b,h,n,d]; Q pre-scaled by QSCALE.
// ---------------------------------------------------------------------------
__global__ __launch_bounds__(256)
void qk_convert(const float* __restrict__ x, unsigned short* __restrict__ Qbf,
                unsigned short* __restrict__ Kbf) {
    int cid = blockIdx.x * 256 + threadIdx.x;  // 2*2*4096*64 chunks of 8
    int d8 = cid & 63;
    int n = (cid >> 6) & 4095;
    int b = (cid >> 18) & 1;
    int c = cid >> 19;
    const float* src = x + (size_t)c * CSTRIDE + ((size_t)(b * 4096 + n)) * 512 + d8 * 8;
    float4 a0 = *reinterpret_cast<const float4*>(src);
    float4 a1 = *reinterpret_cast<const float4*>(src + 4);
    float sc = c ? 1.0f : QSCALE;
    a0.x *= sc; a0.y *= sc; a0.z *= sc; a0.w *= sc;
    a1.x *= sc; a1.y *= sc; a1.z *= sc; a1.w *= sc;
    unsigned short* dst = (c ? Kbf : Qbf) +
        (((size_t)(b * 8 + (d8 >> 3)) * 4096 + n) * 64 + (d8 & 7) * 8);
    *reinterpret_cast<short8*>(dst) = cvt8(a0, a1);
}

// ---------------------------------------------------------------------------
// Prepass 2: V fp32 [b,n,h*64+d] -> bf16 transposed Vt[b,h,d,n]
// ---------------------------------------------------------------------------
__global__ __launch_bounds__(256)
void v_transpose(const float* __restrict__ x, unsigned short* __restrict__ Vt) {
    __shared__ __attribute__((aligned(16))) unsigned short T[64 * 66];
    unsigned* T32 = reinterpret_cast<unsigned*>(T);

    const int tid = threadIdx.x;
    const int bh = blockIdx.y;
    const int b = bh >> 3, h = bh & 7;
    const int n0 = blockIdx.x * 64;

#pragma unroll
    for (int j = 0; j < 2; ++j) {
        int cid = tid + 256 * j;
        int ni = cid >> 3;
        int d0 = (cid & 7) * 8;
        const float* src = x + (size_t)2 * CSTRIDE +
            ((size_t)(b * 4096 + n0 + ni)) * 512 + h * 64 + d0;
        float4 a0 = *reinterpret_cast<const float4*>(src);
        float4 a1 = *reinterpret_cast<const float4*>(src + 4);
        short8 v = cvt8(a0, a1);
#pragma unroll
        for (int k = 0; k < 4; ++k) {
            unsigned pk = (unsigned)(unsigned short)v[2 * k] |
                          ((unsigned)(unsigned short)v[2 * k + 1] << 16);
            T32[ni * 33 + (d0 >> 1) + k] = pk;
        }
    }
    __syncthreads();

#pragma unroll
    for (int j = 0; j < 2; ++j) {
        int cid = tid + 256 * j;
        int di = cid >> 3;
        int k0 = (cid & 7) * 8;
        short8 o;
#pragma unroll
        for (int k = 0; k < 8; ++k) o[k] = (short)T[(k0 + k) * 66 + di];
        unsigned short* dst = Vt + ((size_t)(bh * 64 + di)) * 4096 + n0 + k0;
        *reinterpret_cast<short8*>(dst) = o;
    }
}

// ---------------------------------------------------------------------------
// Prepass 3: W fp32 [512,512] -> bf16
// ---------------------------------------------------------------------------
__global__ __launch_bounds__(256)
void w_convert(const float* __restrict__ W, unsigned short* __restrict__ Wbf) {
    int cid = blockIdx.x * 256 + threadIdx.x;
    int d8 = cid & 63;
    int row = cid >> 6;
    const float* src = W + (size_t)row * 512 + d8 * 8;
    float4 a0 = *reinterpret_cast<const float4*>(src);
    float4 a1 = *reinterpret_cast<const float4*>(src + 4);
    *reinterpret_cast<short8*>(Wbf + (size_t)row * 512 + d8 * 8) = cvt8(a0, a1);
}

// ---------------------------------------------------------------------------
// Flash attention, 32x32x16 MFMA: 64 q-rows/wave (2 subtiles sharing every
// K/V fragment) + IN-BLOCK KV-split (r8's proven pattern).
// grid (32 q-tiles of 128, 16 b*h) = 512 blocks, 4 waves (256 thr):
//   wave w: half = w>>1 (keys half*2048..+2048), qsub = w&1 (64 q-rows).
// Each half's 2 waves stage their own 16KB K+V tile; 2 barriers/step
// (proven r8 protocol). End: in-LDS fp32 add-combine (aliases staging).
// No max tracking (log2-unit scores, |S| <= ~10; fp32 margin ~2^100).
// ---------------------------------------------------------------------------
#define SMEM_BYTES (32768 + 512)  // 2x(K+V tile) staging / Xo fp32 + Xl

__global__ __launch_bounds__(256, 2)
void attn_kernel(const unsigned short* __restrict__ Qbf,
                 const unsigned short* __restrict__ Kbf,
                 const unsigned short* __restrict__ Vt,
                 unsigned short* __restrict__ Obf) {
    __shared__ __attribute__((aligned(16))) unsigned char SMEM[SMEM_BYTES];

    const int tid = threadIdx.x;
    const int lane = tid & 63;
    const int wv = tid >> 6;    // 0..3
    const int hi = lane >> 5;
    const int l5 = lane & 31;
    const int half = wv >> 1;   // KV half
    const int qs = wv & 1;      // q-sub-block (64 rows)

    const int bh = blockIdx.y;
    const int b = bh >> 3, h = bh & 7;
    const int qbase = blockIdx.x * 128 + qs * 64;

    const unsigned short* Qh = Qbf + (size_t)bh * NSEQ * HD;
    const unsigned short* Kh = Kbf + (size_t)bh * NSEQ * HD;
    const unsigned short* Vh = Vt + (size_t)bh * HD * NSEQ;

    char* K_lds = (char*)SMEM + half * 16384;
    char* V_lds = K_lds + 8192;

    // Q fragments (B-operand): lane holds Q[q = u*32+l5][d = c*16 + hi*8 + j]
    short8 qf[2][4];
#pragma unroll
    for (int u = 0; u < 2; ++u)
#pragma unroll
        for (int c = 0; c < 4; ++c)
            qf[u][c] = *reinterpret_cast<const short8*>(
                Qh + (size_t)(qbase + u * 32 + l5) * HD + c * 16 + hi * 8);

    f32x16 oacc[2][2];
#pragma unroll
    for (int u = 0; u < 2; ++u)
#pragma unroll
        for (int db = 0; db < 2; ++db)
#pragma unroll
            for (int r = 0; r < 16; ++r) oacc[u][db][r] = 0.f;
    float l_run[2] = {0.f, 0.f};

    // staging: each half's 128 threads stage one 64x64 K and V tile (4 chunks each)
    const int gt = tid & 127;
    const int kt0 = half * 32;
    int srow[4], se0[4], soff[4];
#pragma unroll
    for (int c = 0; c < 4; ++c) {
        int chunk = gt + 128 * c;
        srow[c] = chunk >> 3;
        se0[c] = (chunk & 7) * 8;
        soff[c] = (srow[c] * 128 + se0[c] * 2) ^ ((srow[c] & 7) << 4);
    }
    const int swz = (l5 & 7) << 4;

    // preload tile kt0
    short8 kreg[4], vreg[4];
#pragma unroll
    for (int c = 0; c < 4; ++c) {
        kreg[c] = *reinterpret_cast<const short8*>(Kh + (size_t)(kt0 * 64 + srow[c]) * HD + se0[c]);
        vreg[c] = *reinterpret_cast<const short8*>(Vh + (size_t)srow[c] * NSEQ + kt0 * 64 + se0[c]);
    }

    for (int step = 0; step < 32; ++step) {
        __syncthreads();  // everyone done reading prev tile
#pragma unroll
        for (int c = 0; c < 4; ++c) {
            *reinterpret_cast<short8*>(K_lds + soff[c]) = kreg[c];
            *reinterpret_cast<short8*>(V_lds + soff[c]) = vreg[c];
        }
        {   // prefetch next tile (wraps within half, harmless on last iter)
            int nt = kt0 + ((step + 1) & 31);
#pragma unroll
            for (int c = 0; c < 4; ++c) {
                kreg[c] = *reinterpret_cast<const short8*>(
                    Kh + (size_t)(nt * 64 + srow[c]) * HD + se0[c]);
                vreg[c] = *reinterpret_cast<const short8*>(
                    Vh + (size_t)srow[c] * NSEQ + nt * 64 + se0[c]);
            }
        }
        __syncthreads();  // LDS tile ready

        // ---- S^T = K Q^T for BOTH subtiles; each kf feeds 2 MFMAs ----
        // lane holds S[key = kb*32+(r&3)+8*(r>>2)+4*hi][q = u*32+l5]
        f32x16 st[2][2];
        __builtin_amdgcn_s_setprio(1);
#pragma unroll
        for (int kb = 0; kb < 2; ++kb) {
            f32x16 aA, aB;
#pragma unroll
            for (int r = 0; r < 16; ++r) { aA[r] = 0.f; aB[r] = 0.f; }
#pragma unroll
            for (int c = 0; c < 4; ++c) {
                int key = kb * 32 + l5;
                short8 kf = *reinterpret_cast<const short8*>(
                    K_lds + ((key * 128 + c * 32 + hi * 16) ^ swz));
                aA = MFMA32(kf, qf[0][c], aA);
                aB = MFMA32(kf, qf[1][c], aB);
            }
            st[0][kb] = aA;
            st[1][kb] = aB;
        }
        __builtin_amdgcn_s_setprio(0);

        // ---- p = exp2(S); l row-sums on VALU ----
#pragma unroll
        for (int u = 0; u < 2; ++u) {
#pragma unroll
            for (int kb = 0; kb < 2; ++kb)
#pragma unroll
                for (int r = 0; r < 16; ++r)
                    st[u][kb][r] = __builtin_amdgcn_exp2f(st[u][kb][r]);
            float s = 0.f;
#pragma unroll
            for (int r = 0; r < 16; ++r) s += st[u][0][r] + st[u][1][r];
            s += __shfl_xor(s, 32);  // add other half-wave's 32 keys
            l_run[u] += s;           // lane l holds l for q = u*32 + (l&31)
        }

        // ---- P^T -> PV A-fragments (cvt_pk + shfl_xor + select), per subtile ----
        short8 PA[2][4];
#pragma unroll
        for (int u = 0; u < 2; ++u)
#pragma unroll
            for (int kb = 0; kb < 2; ++kb)
#pragma unroll
                for (int ks = 0; ks < 2; ++ks) {
                    unsigned c0 = cvt_pk_bf16(st[u][kb][8 * ks + 0], st[u][kb][8 * ks + 1]);
                    unsigned c1 = cvt_pk_bf16(st[u][kb][8 * ks + 2], st[u][kb][8 * ks + 3]);
                    unsigned c2 = cvt_pk_bf16(st[u][kb][8 * ks + 4], st[u][kb][8 * ks + 5]);
                    unsigned c3 = cvt_pk_bf16(st[u][kb][8 * ks + 6], st[u][kb][8 * ks + 7]);
                    unsigned d0 = (unsigned)__shfl_xor((int)c0, 32);
                    unsigned d1 = (unsigned)__shfl_xor((int)c1, 32);
                    unsigned d2 = (unsigned)__shfl_xor((int)c2, 32);
                    unsigned d3 = (unsigned)__shfl_xor((int)c3, 32);
                    uint4v w;
                    w[0] = hi ? d2 : c0;
                    w[1] = hi ? d3 : c1;
                    w[2] = hi ? c2 : d0;
                    w[3] = hi ? c3 : d1;
                    PA[u][kb * 2 + ks] = __builtin_bit_cast(short8, w);
                }

        // ---- PV for both subtiles; each vf feeds 2 MFMAs ----
        __builtin_amdgcn_s_setprio(1);
#pragma unroll
        for (int ch = 0; ch < 4; ++ch) {
#pragma unroll
            for (int db = 0; db < 2; ++db) {
                int d = db * 32 + l5;
                short8 vf = *reinterpret_cast<const short8*>(
                    V_lds + ((d * 128 + ch * 32 + hi * 16) ^ swz));
                oacc[0][db] = MFMA32(PA[0][ch], vf, oacc[0][db]);
                oacc[1][db] = MFMA32(PA[1][ch], vf, oacc[1][db]);
            }
        }
        __builtin_amdgcn_s_setprio(0);
    }

    // ---- in-LDS fp32 add-combine: half 1 -> Xo/Xl; half 0 merges + writes ----
    float* Xo = (float*)SMEM;             // [128 q][64 d] fp32 (aliases staging)
    float* Xl = (float*)(SMEM + 32768);   // [128]

    __syncthreads();  // all staging reads done; LDS reusable
    if (half == 1) {
#pragma unroll
        for (int u = 0; u < 2; ++u) {
#pragma unroll
            for (int r = 0; r < 16; ++r) {
                int crow = (r & 3) + 8 * (r >> 2) + 4 * hi;
                int qloc = qs * 64 + u * 32 + crow;
                Xo[qloc * 64 + l5] = oacc[u][0][r];
                Xo[qloc * 64 + 32 + l5] = oacc[u][1][r];
            }
            if (hi == 0) Xl[qs * 64 + u * 32 + l5] = l_run[u];
        }
    }
    __syncthreads();
    if (half == 0) {
#pragma unroll
        for (int u = 0; u < 2; ++u) {
#pragma unroll
            for (int r = 0; r < 16; ++r) {
                int crow = (r & 3) + 8 * (r >> 2) + 4 * hi;
                int qloc = qs * 64 + u * 32 + crow;
                float l1 = Xl[qloc];
                float inv = 1.0f / (__shfl(l_run[u], crow) + l1);
                float v0 = oacc[u][0][r] + Xo[qloc * 64 + l5];
                float v1 = oacc[u][1][r] + Xo[qloc * 64 + 32 + l5];
                int qrow = qbase + u * 32 + crow;
                size_t obase = (size_t)(b * NSEQ + qrow) * DMODEL + h * HD;
                Obf[obase + l5] = f2bf(v0 * inv);
                Obf[obase + 32 + l5] = f2bf(v1 * inv);
            }
        }
    }
}

// ---------------------------------------------------------------------------
// Projection: Y[8192,512] = O_bf16 @ Wbf^T + bias
// ---------------------------------------------------------------------------
__global__ __launch_bounds__(256, 4)
void proj_kernel(const unsigned short* __restrict__ Obf, const unsigned short* __restrict__ Wbf,
                 const float* __restrict__ bias, float* __restrict__ out) {
    __shared__ __attribute__((aligned(16))) unsigned short W_lds[64 * 64];  // [j][k] swz

    const int tid = threadIdx.x;
    const int lane = tid & 63;
    const int wv = tid >> 6;
    const int g = lane >> 4;
    const int l4 = lane & 15;

    const int bm = blockIdx.x;
    const int bn = blockIdx.y;

    f32x4 acc[4];
#pragma unroll
    for (int jt = 0; jt < 4; ++jt) acc[jt] = (f32x4){0.f, 0.f, 0.f, 0.f};

    for (int kc = 0; kc < DMODEL / 64; ++kc) {
#pragma unroll
        for (int j = 0; j < 2; ++j) {
            int cid = tid + 256 * j;
            int row = cid >> 3;
            int ee = (cid & 7) * 8;
            short8 wv8 = *reinterpret_cast<const short8*>(
                Wbf + (size_t)(bn * 64 + row) * DMODEL + kc * 64 + ee);
            int off = (row * 128 + ee * 2) ^ ((row & 7) << 4);
            *reinterpret_cast<short8*>((char*)W_lds + off) = wv8;
        }
        __syncthreads();

#pragma unroll
        for (int sub = 0; sub < 2; ++sub) {
            const unsigned short* ap =
                Obf + (size_t)(bm * 64 + wv * 16 + l4) * DMODEL + kc * 64 + sub * 32 + g * 8;
            short8 a = *reinterpret_cast<const short8*>(ap);
#pragma unroll
            for (int jt = 0; jt < 4; ++jt) {
                int jj = jt * 16 + l4;
                int off = (jj * 128 + (sub * 32 + g * 8) * 2) ^ ((jj & 7) << 4);
                short8 wb = *reinterpret_cast<const short8*>((const char*)W_lds + off);
                acc[jt] = MFMA16(a, wb, acc[jt]);
            }
        }
        __syncthreads();
    }

#pragma unroll
    for (int jt = 0; jt < 4; ++jt) {
        int jg = bn * 64 + jt * 16 + l4;
        float bj = bias[jg];
#pragma unroll
        for (int r = 0; r < 4; ++r) {
            int ig = bm * 64 + wv * 16 + g * 4 + r;
            out[(size_t)ig * DMODEL + jg] = acc[jt][r] + bj;
        }
    }
}

extern "C" void kernel_launch(void* const* d_in, const int* in_sizes, int n_in,
                              void* d_out, int out_size, void* d_ws, size_t ws_size,
                              hipStream_t stream) {
    const float* x = (const float*)d_in[0];     // [3, 2, 4096, 512] fp32
    const float* W = (const float*)d_in[1];     // [512, 512] fp32
    const float* bias = (const float*)d_in[2];  // [512] fp32
    float* out = (float*)d_out;                 // [2, 4096, 512] fp32

    // workspace layout — identical to the proven round-8 footprint (32.5 MB):
    char* ws = (char*)d_ws;
    unsigned short* Obf = (unsigned short*)(ws);                // [0, 8MB)
    unsigned short* Qbf = (unsigned short*)(ws + (8u << 20));   // [8, 16)
    unsigned short* Kbf = (unsigned short*)(ws + (16u << 20));  // [16, 24)
    unsigned short* Vt = (unsigned short*)(ws + (24u << 20));   // [24, 32)
    unsigned short* Wbf = (unsigned short*)(ws + (32u << 20));  // [32, 32.5)

    qk_convert<<<4096, 256, 0, stream>>>(x, Qbf, Kbf);
    v_transpose<<<dim3(NSEQ / 64, NB * NH), 256, 0, stream>>>(x, Vt);
    w_convert<<<128, 256, 0, stream>>>(W, Wbf);

    dim3 gA(NSEQ / 128, NB * NH);  // (32, 16) = 512 blocks x 4 waves
    attn_kernel<<<gA, 256, 0, stream>>>(Qbf, Kbf, Vt, Obf);

    dim3 gP(NB * NSEQ / 64, DMODEL / 64);  // (128, 8)
    proj_kernel<<<gP, 256, 0, stream>>>(Obf, Wbf, bias, out);
}

// Round 13
// 129.367 us; speedup vs baseline: 1.0719x; 1.0719x over previous
//
#include <hip/hip_runtime.h>
#include <hip/hip_bf16.h>

typedef __attribute__((ext_vector_type(8))) short short8;
typedef __attribute__((ext_vector_type(4))) float f32x4;
typedef __attribute__((ext_vector_type(16))) float f32x16;
typedef __attribute__((ext_vector_type(4))) unsigned uint4v;

#define MFMA16(a, b, c) __builtin_amdgcn_mfma_f32_16x16x32_bf16((a), (b), (c), 0, 0, 0)
#define MFMA32(a, b, c) __builtin_amdgcn_mfma_f32_32x32x16_bf16((a), (b), (c), 0, 0, 0)

// dims
#define NB 2
#define NSEQ 4096
#define DMODEL 512
#define NH 8
#define HD 64
#define CSTRIDE (NB * NSEQ * DMODEL)  // 4194304

#define QSCALE 0.18033688011112042f  // 0.125 * log2(e), folded into Q prepass

static __device__ __forceinline__ unsigned short f2bf(float f) {
    unsigned u = __builtin_bit_cast(unsigned, f);
    u += 0x7fffu + ((u >> 16) & 1u);
    return (unsigned short)(u >> 16);
}

static __device__ __forceinline__ short8 cvt8(float4 a, float4 b) {
    short8 r;
    r[0] = (short)f2bf(a.x); r[1] = (short)f2bf(a.y);
    r[2] = (short)f2bf(a.z); r[3] = (short)f2bf(a.w);
    r[4] = (short)f2bf(b.x); r[5] = (short)f2bf(b.y);
    r[6] = (short)f2bf(b.z); r[7] = (short)f2bf(b.w);
    return r;
}

static __device__ __forceinline__ unsigned cvt_pk_bf16(float lo, float hi) {
    unsigned r;
    asm("v_cvt_pk_bf16_f32 %0, %1, %2" : "=v"(r) : "v"(lo), "v"(hi));
    return r;
}

// async global -> LDS, 16B per lane; lds dest must be wave-uniform base
static __device__ __forceinline__ void gload_lds16(const void* g, void* l) {
    __builtin_amdgcn_global_load_lds(
        (const __attribute__((address_space(1))) void*)g,
        (__attribute__((address_space(3))) void*)l, 16, 0, 0);
}

// ---------------------------------------------------------------------------
// Prepass 1: Q,K fp32 [b,n,h*64+d] -> bf16 [b,h,n,d]; Q pre-scaled by QSCALE.
// ---------------------------------------------------------------------------
__global__ __launch_bounds__(256)
void qk_convert(const float* __restrict__ x, unsigned short* __restrict__ Qbf,
                unsigned short* __restrict__ Kbf) {
    int cid = blockIdx.x * 256 + threadIdx.x;  // 2*2*4096*64 chunks of 8
    int d8 = cid & 63;
    int n = (cid >> 6) & 4095;
    int b = (cid >> 18) & 1;
    int c = cid >> 19;
    const float* src = x + (size_t)c * CSTRIDE + ((size_t)(b * 4096 + n)) * 512 + d8 * 8;
    float4 a0 = *reinterpret_cast<const float4*>(src);
    float4 a1 = *reinterpret_cast<const float4*>(src + 4);
    float sc = c ? 1.0f : QSCALE;
    a0.x *= sc; a0.y *= sc; a0.z *= sc; a0.w *= sc;
    a1.x *= sc; a1.y *= sc; a1.z *= sc; a1.w *= sc;
    unsigned short* dst = (c ? Kbf : Qbf) +
        (((size_t)(b * 8 + (d8 >> 3)) * 4096 + n) * 64 + (d8 & 7) * 8);
    *reinterpret_cast<short8*>(dst) = cvt8(a0, a1);
}

// ---------------------------------------------------------------------------
// Prepass 2: V fp32 [b,n,h*64+d] -> bf16 transposed Vt[b,h,d,n]
// ---------------------------------------------------------------------------
__global__ __launch_bounds__(256)
void v_transpose(const float* __restrict__ x, unsigned short* __restrict__ Vt) {
    __shared__ __attribute__((aligned(16))) unsigned short T[64 * 66];
    unsigned* T32 = reinterpret_cast<unsigned*>(T);

    const int tid = threadIdx.x;
    const int bh = blockIdx.y;
    const int b = bh >> 3, h = bh & 7;
    const int n0 = blockIdx.x * 64;

#pragma unroll
    for (int j = 0; j < 2; ++j) {
        int cid = tid + 256 * j;
        int ni = cid >> 3;
        int d0 = (cid & 7) * 8;
        const float* src = x + (size_t)2 * CSTRIDE +
            ((size_t)(b * 4096 + n0 + ni)) * 512 + h * 64 + d0;
        float4 a0 = *reinterpret_cast<const float4*>(src);
        float4 a1 = *reinterpret_cast<const float4*>(src + 4);
        short8 v = cvt8(a0, a1);
#pragma unroll
        for (int k = 0; k < 4; ++k) {
            unsigned pk = (unsigned)(unsigned short)v[2 * k] |
                          ((unsigned)(unsigned short)v[2 * k + 1] << 16);
            T32[ni * 33 + (d0 >> 1) + k] = pk;
        }
    }
    __syncthreads();

#pragma unroll
    for (int j = 0; j < 2; ++j) {
        int cid = tid + 256 * j;
        int di = cid >> 3;
        int k0 = (cid & 7) * 8;
        short8 o;
#pragma unroll
        for (int k = 0; k < 8; ++k) o[k] = (short)T[(k0 + k) * 66 + di];
        unsigned short* dst = Vt + ((size_t)(bh * 64 + di)) * 4096 + n0 + k0;
        *reinterpret_cast<short8*>(dst) = o;
    }
}

// ---------------------------------------------------------------------------
// Prepass 3: W fp32 [512,512] -> bf16
// ---------------------------------------------------------------------------
__global__ __launch_bounds__(256)
void w_convert(const float* __restrict__ W, unsigned short* __restrict__ Wbf) {
    int cid = blockIdx.x * 256 + threadIdx.x;
    int d8 = cid & 63;
    int row = cid >> 6;
    const float* src = W + (size_t)row * 512 + d8 * 8;
    float4 a0 = *reinterpret_cast<const float4*>(src);
    float4 a1 = *reinterpret_cast<const float4*>(src + 4);
    *reinterpret_cast<short8*>(Wbf + (size_t)row * 512 + d8 * 8) = cvt8(a0, a1);
}

// ---------------------------------------------------------------------------
// Flash attention, 32x32x16 MFMA: 64 q-rows/wave (2 subtiles sharing every
// K/V fragment) + in-block KV-split; ASYNC global_load_lds staging with
// pre-swizzled global source, double-buffered, ONE barrier per step.
// grid (32 q-tiles of 128, 16 b*h) = 512 blocks, 4 waves (256 thr):
//   wave w: half = w>>1 (keys half*2048..+2048), qsub = w&1 (64 q-rows).
// End: in-LDS fp32 add-combine (aliases staging; no DMA in flight there).
// No max tracking (log2-unit scores, |S| <= ~10; fp32 margin ~2^100).
// ---------------------------------------------------------------------------
#define SMEM_BYTES 65536  // 2 halves x 2 bufs x (K 8K + V 8K); combine aliases

__global__ __launch_bounds__(256, 2)
void attn_kernel(const unsigned short* __restrict__ Qbf,
                 const unsigned short* __restrict__ Kbf,
                 const unsigned short* __restrict__ Vt,
                 unsigned short* __restrict__ Obf) {
    __shared__ __attribute__((aligned(16))) unsigned char SMEM[SMEM_BYTES];

    const int tid = threadIdx.x;
    const int lane = tid & 63;
    const int wv = tid >> 6;    // 0..3
    const int hi = lane >> 5;
    const int l5 = lane & 31;
    const int half = wv >> 1;   // KV half
    const int qs = wv & 1;      // q-sub-block (64 rows)
    const int w2 = wv & 1;      // staging role within half

    const int bh = blockIdx.y;
    const int b = bh >> 3, h = bh & 7;
    const int qbase = blockIdx.x * 128 + qs * 64;

    const unsigned short* Qh = Qbf + (size_t)bh * NSEQ * HD;
    const unsigned short* Kh = Kbf + (size_t)bh * NSEQ * HD;
    const unsigned short* Vh = Vt + (size_t)bh * HD * NSEQ;

    char* K_base = (char*)SMEM + half * 32768;  // [buf0: K 8K | V 8K][buf1: ...]

    // Q fragments (B-operand): lane holds Q[q = u*32+l5][d = c*16 + hi*8 + j]
    short8 qf[2][4];
#pragma unroll
    for (int u = 0; u < 2; ++u)
#pragma unroll
        for (int c = 0; c < 4; ++c)
            qf[u][c] = *reinterpret_cast<const short8*>(
                Qh + (size_t)(qbase + u * 32 + l5) * HD + c * 16 + hi * 8);

    f32x16 zero16;
#pragma unroll
    for (int r = 0; r < 16; ++r) zero16[r] = 0.f;

    f32x16 oacc[2][2];
#pragma unroll
    for (int u = 0; u < 2; ++u)
#pragma unroll
        for (int db = 0; db < 2; ++db) oacc[u][db] = zero16;
    float l_run[2] = {0.f, 0.f};

    const int kt0 = half * 32;
    const int swz = (l5 & 7) << 4;

    // pre-swizzled source addressing for linear gload_lds dest:
    // chunk j (0..7), lane l: LDS byte L = j*1024 + l*16 ->
    //   row = j*8 + (l>>3); elem e = ((l&7)*8) ^ ((row&7)*8)
    const int lrow = lane >> 3;                       // 0..7
    const int lelem = ((lane & 7) * 8) ^ (lrow * 8);  // pre-swizzled elem offset

    // prologue: issue tile kt0 -> buf 0
    {
        char* Kb = K_base;
        char* Vb = K_base + 8192;
#pragma unroll
        for (int i = 0; i < 4; ++i) {
            int j = w2 * 4 + i;
            int row = j * 8 + lrow;
            gload_lds16(Kh + (size_t)(kt0 * 64 + row) * HD + lelem, Kb + j * 1024);
            gload_lds16(Vh + (size_t)row * NSEQ + kt0 * 64 + lelem, Vb + j * 1024);
        }
    }
    __syncthreads();  // implicit vmcnt(0) drain: buf0 ready

    int cur = 0;
    for (int step = 0; step < 32; ++step) {
        // issue async loads for tile step+1 into buf[cur^1] (free since the
        // barrier ending step-1). Skip at step 31 (combine aliases LDS).
        if (step < 31) {
            int nt = kt0 + step + 1;
            char* Kb = K_base + (cur ^ 1) * 16384;
            char* Vb = Kb + 8192;
#pragma unroll
            for (int i = 0; i < 4; ++i) {
                int j = w2 * 4 + i;
                int row = j * 8 + lrow;
                gload_lds16(Kh + (size_t)(nt * 64 + row) * HD + lelem, Kb + j * 1024);
                gload_lds16(Vh + (size_t)row * NSEQ + nt * 64 + lelem, Vb + j * 1024);
            }
        }

        const char* K_lds = K_base + cur * 16384;
        const char* V_lds = K_lds + 8192;

        // ---- S^T = K Q^T for BOTH subtiles; each kf feeds 2 MFMAs ----
        // lane holds S[key = kb*32+(r&3)+8*(r>>2)+4*hi][q = u*32+l5]
        f32x16 st[2][2];
        __builtin_amdgcn_s_setprio(1);
#pragma unroll
        for (int kb = 0; kb < 2; ++kb) {
            int key = kb * 32 + l5;
            short8 kf0 = *reinterpret_cast<const short8*>(
                K_lds + ((key * 128 + 0 * 32 + hi * 16) ^ swz));
            f32x16 aA = MFMA32(kf0, qf[0][0], zero16);
            f32x16 aB = MFMA32(kf0, qf[1][0], zero16);
#pragma unroll
            for (int c = 1; c < 4; ++c) {
                short8 kf = *reinterpret_cast<const short8*>(
                    K_lds + ((key * 128 + c * 32 + hi * 16) ^ swz));
                aA = MFMA32(kf, qf[0][c], aA);
                aB = MFMA32(kf, qf[1][c], aB);
            }
            st[0][kb] = aA;
            st[1][kb] = aB;
        }
        __builtin_amdgcn_s_setprio(0);

        // ---- p = exp2(S); l row-sums on VALU ----
#pragma unroll
        for (int u = 0; u < 2; ++u) {
#pragma unroll
            for (int kb = 0; kb < 2; ++kb)
#pragma unroll
                for (int r = 0; r < 16; ++r)
                    st[u][kb][r] = __builtin_amdgcn_exp2f(st[u][kb][r]);
            float s = 0.f;
#pragma unroll
            for (int r = 0; r < 16; ++r) s += st[u][0][r] + st[u][1][r];
            s += __shfl_xor(s, 32);  // add other half-wave's 32 keys
            l_run[u] += s;           // lane l holds l for q = u*32 + (l&31)
        }

        // ---- P^T -> PV A-fragments (cvt_pk + shfl_xor + select), per subtile ----
        short8 PA[2][4];
#pragma unroll
        for (int u = 0; u < 2; ++u)
#pragma unroll
            for (int kb = 0; kb < 2; ++kb)
#pragma unroll
                for (int ks = 0; ks < 2; ++ks) {
                    unsigned c0 = cvt_pk_bf16(st[u][kb][8 * ks + 0], st[u][kb][8 * ks + 1]);
                    unsigned c1 = cvt_pk_bf16(st[u][kb][8 * ks + 2], st[u][kb][8 * ks + 3]);
                    unsigned c2 = cvt_pk_bf16(st[u][kb][8 * ks + 4], st[u][kb][8 * ks + 5]);
                    unsigned c3 = cvt_pk_bf16(st[u][kb][8 * ks + 6], st[u][kb][8 * ks + 7]);
                    unsigned d0 = (unsigned)__shfl_xor((int)c0, 32);
                    unsigned d1 = (unsigned)__shfl_xor((int)c1, 32);
                    unsigned d2 = (unsigned)__shfl_xor((int)c2, 32);
                    unsigned d3 = (unsigned)__shfl_xor((int)c3, 32);
                    uint4v w;
                    w[0] = hi ? d2 : c0;
                    w[1] = hi ? d3 : c1;
                    w[2] = hi ? c2 : d0;
                    w[3] = hi ? c3 : d1;
                    PA[u][kb * 2 + ks] = __builtin_bit_cast(short8, w);
                }

        // ---- PV for both subtiles; each vf feeds 2 MFMAs ----
        __builtin_amdgcn_s_setprio(1);
#pragma unroll
        for (int ch = 0; ch < 4; ++ch) {
#pragma unroll
            for (int db = 0; db < 2; ++db) {
                int d = db * 32 + l5;
                short8 vf = *reinterpret_cast<const short8*>(
                    V_lds + ((d * 128 + ch * 32 + hi * 16) ^ swz));
                oacc[0][db] = MFMA32(PA[0][ch], vf, oacc[0][db]);
                oacc[1][db] = MFMA32(PA[1][ch], vf, oacc[1][db]);
            }
        }
        __builtin_amdgcn_s_setprio(0);

        __syncthreads();  // drains this wave's DMA (vmcnt) + LDS reads; swap
        cur ^= 1;
    }

    // ---- in-LDS fp32 add-combine: half 1 -> Xo/Xl; half 0 merges + writes ----
    float* Xo = (float*)SMEM;             // [128 q][64 d] fp32 (aliases staging)
    float* Xl = (float*)(SMEM + 32768);   // [128]

    if (half == 1) {
#pragma unroll
        for (int u = 0; u < 2; ++u) {
#pragma unroll
            for (int r = 0; r < 16; ++r) {
                int crow = (r & 3) + 8 * (r >> 2) + 4 * hi;
                int qloc = qs * 64 + u * 32 + crow;
                Xo[qloc * 64 + l5] = oacc[u][0][r];
                Xo[qloc * 64 + 32 + l5] = oacc[u][1][r];
            }
            if (hi == 0) Xl[qs * 64 + u * 32 + l5] = l_run[u];
        }
    }
    __syncthreads();
    if (half == 0) {
#pragma unroll
        for (int u = 0; u < 2; ++u) {
#pragma unroll
            for (int r = 0; r < 16; ++r) {
                int crow = (r & 3) + 8 * (r >> 2) + 4 * hi;
                int qloc = qs * 64 + u * 32 + crow;
                float l1 = Xl[qloc];
                float inv = 1.0f / (__shfl(l_run[u], crow) + l1);
                float v0 = oacc[u][0][r] + Xo[qloc * 64 + l5];
                float v1 = oacc[u][1][r] + Xo[qloc * 64 + 32 + l5];
                int qrow = qbase + u * 32 + crow;
                size_t obase = (size_t)(b * NSEQ + qrow) * DMODEL + h * HD;
                Obf[obase + l5] = f2bf(v0 * inv);
                Obf[obase + 32 + l5] = f2bf(v1 * inv);
            }
        }
    }
}

// ---------------------------------------------------------------------------
// Projection: Y[8192,512] = O_bf16 @ Wbf^T + bias
// ---------------------------------------------------------------------------
__global__ __launch_bounds__(256, 4)
void proj_kernel(const unsigned short* __restrict__ Obf, const unsigned short* __restrict__ Wbf,
                 const float* __restrict__ bias, float* __restrict__ out) {
    __shared__ __attribute__((aligned(16))) unsigned short W_lds[64 * 64];  // [j][k] swz

    const int tid = threadIdx.x;
    const int lane = tid & 63;
    const int wv = tid >> 6;
    const int g = lane >> 4;
    const int l4 = lane & 15;

    const int bm = blockIdx.x;
    const int bn = blockIdx.y;

    f32x4 acc[4];
#pragma unroll
    for (int jt = 0; jt < 4; ++jt) acc[jt] = (f32x4){0.f, 0.f, 0.f, 0.f};

    for (int kc = 0; kc < DMODEL / 64; ++kc) {
#pragma unroll
        for (int j = 0; j < 2; ++j) {
            int cid = tid + 256 * j;
            int row = cid >> 3;
            int ee = (cid & 7) * 8;
            short8 wv8 = *reinterpret_cast<const short8*>(
                Wbf + (size_t)(bn * 64 + row) * DMODEL + kc * 64 + ee);
            int off = (row * 128 + ee * 2) ^ ((row & 7) << 4);
            *reinterpret_cast<short8*>((char*)W_lds + off) = wv8;
        }
        __syncthreads();

#pragma unroll
        for (int sub = 0; sub < 2; ++sub) {
            const unsigned short* ap =
                Obf + (size_t)(bm * 64 + wv * 16 + l4) * DMODEL + kc * 64 + sub * 32 + g * 8;
            short8 a = *reinterpret_cast<const short8*>(ap);
#pragma unroll
            for (int jt = 0; jt < 4; ++jt) {
                int jj = jt * 16 + l4;
                int off = (jj * 128 + (sub * 32 + g * 8) * 2) ^ ((jj & 7) << 4);
                short8 wb = *reinterpret_cast<const short8*>((const char*)W_lds + off);
                acc[jt] = MFMA16(a, wb, acc[jt]);
            }
        }
        __syncthreads();
    }

#pragma unroll
    for (int jt = 0; jt < 4; ++jt) {
        int jg = bn * 64 + jt * 16 + l4;
        float bj = bias[jg];
#pragma unroll
        for (int r = 0; r < 4; ++r) {
            int ig = bm * 64 + wv * 16 + g * 4 + r;
            out[(size_t)ig * DMODEL + jg] = acc[jt][r] + bj;
        }
    }
}

extern "C" void kernel_launch(void* const* d_in, const int* in_sizes, int n_in,
                              void* d_out, int out_size, void* d_ws, size_t ws_size,
                              hipStream_t stream) {
    const float* x = (const float*)d_in[0];     // [3, 2, 4096, 512] fp32
    const float* W = (const float*)d_in[1];     // [512, 512] fp32
    const float* bias = (const float*)d_in[2];  // [512] fp32
    float* out = (float*)d_out;                 // [2, 4096, 512] fp32

    // workspace layout — identical to the proven round-8 footprint (32.5 MB):
    char* ws = (char*)d_ws;
    unsigned short* Obf = (unsigned short*)(ws);                // [0, 8MB)
    unsigned short* Qbf = (unsigned short*)(ws + (8u << 20));   // [8, 16)
    unsigned short* Kbf = (unsigned short*)(ws + (16u << 20));  // [16, 24)
    unsigned short* Vt = (unsigned short*)(ws + (24u << 20));   // [24, 32)
    unsigned short* Wbf = (unsigned short*)(ws + (32u << 20));  // [32, 32.5)

    qk_convert<<<4096, 256, 0, stream>>>(x, Qbf, Kbf);
    v_transpose<<<dim3(NSEQ / 64, NB * NH), 256, 0, stream>>>(x, Vt);
    w_convert<<<128, 256, 0, stream>>>(W, Wbf);

    dim3 gA(NSEQ / 128, NB * NH);  // (32, 16) = 512 blocks x 4 waves
    attn_kernel<<<gA, 256, 0, stream>>>(Qbf, Kbf, Vt, Obf);

    dim3 gP(NB * NSEQ / 64, DMODEL / 64);  // (128, 8)
    proj_kernel<<<gP, 256, 0, stream>>>(Obf, Wbf, bias, out);
}

// Round 14
// 124.320 us; speedup vs baseline: 1.1154x; 1.0406x over previous
//
#include <hip/hip_runtime.h>
#include <hip/hip_bf16.h>

typedef __attribute__((ext_vector_type(8))) short short8;
typedef __attribute__((ext_vector_type(4))) float f32x4;
typedef __attribute__((ext_vector_type(16))) float f32x16;
typedef __attribute__((ext_vector_type(4))) unsigned uint4v;

#define MFMA16(a, b, c) __builtin_amdgcn_mfma_f32_16x16x32_bf16((a), (b), (c), 0, 0, 0)
#define MFMA32(a, b, c) __builtin_amdgcn_mfma_f32_32x32x16_bf16((a), (b), (c), 0, 0, 0)

// dims
#define NB 2
#define NSEQ 4096
#define DMODEL 512
#define NH 8
#define HD 64
#define CSTRIDE (NB * NSEQ * DMODEL)  // 4194304

#define QSCALE 0.18033688011112042f  // 0.125 * log2(e), applied to Q in-kernel

static __device__ __forceinline__ unsigned short f2bf(float f) {
    unsigned u = __builtin_bit_cast(unsigned, f);
    u += 0x7fffu + ((u >> 16) & 1u);
    return (unsigned short)(u >> 16);
}

static __device__ __forceinline__ short8 cvt8(float4 a, float4 b) {
    short8 r;
    r[0] = (short)f2bf(a.x); r[1] = (short)f2bf(a.y);
    r[2] = (short)f2bf(a.z); r[3] = (short)f2bf(a.w);
    r[4] = (short)f2bf(b.x); r[5] = (short)f2bf(b.y);
    r[6] = (short)f2bf(b.z); r[7] = (short)f2bf(b.w);
    return r;
}

static __device__ __forceinline__ unsigned cvt_pk_bf16(float lo, float hi) {
    unsigned r;
    asm("v_cvt_pk_bf16_f32 %0, %1, %2" : "=v"(r) : "v"(lo), "v"(hi));
    return r;
}

// async global -> LDS, 16B per lane; lds dest must be wave-uniform base
static __device__ __forceinline__ void gload_lds16(const void* g, void* l) {
    __builtin_amdgcn_global_load_lds(
        (const __attribute__((address_space(1))) void*)g,
        (__attribute__((address_space(3))) void*)l, 16, 0, 0);
}

// ---------------------------------------------------------------------------
// Prepass 1: K fp32 [b,n,h*64+d] -> bf16 [b,h,n,d]
// ---------------------------------------------------------------------------
__global__ __launch_bounds__(256)
void k_convert(const float* __restrict__ x, unsigned short* __restrict__ Kbf) {
    int cid = blockIdx.x * 256 + threadIdx.x;  // 2*4096*64 chunks of 8
    int d8 = cid & 63;
    int n = (cid >> 6) & 4095;
    int b = cid >> 18;
    const float* src = x + (size_t)CSTRIDE + ((size_t)(b * 4096 + n)) * 512 + d8 * 8;
    float4 a0 = *reinterpret_cast<const float4*>(src);
    float4 a1 = *reinterpret_cast<const float4*>(src + 4);
    unsigned short* dst = Kbf +
        (((size_t)(b * 8 + (d8 >> 3)) * 4096 + n) * 64 + (d8 & 7) * 8);
    *reinterpret_cast<short8*>(dst) = cvt8(a0, a1);
}

// ---------------------------------------------------------------------------
// Prepass 2: V fp32 [b,n,h*64+d] -> bf16 transposed Vt[b,h,d,n]
// ---------------------------------------------------------------------------
__global__ __launch_bounds__(256)
void v_transpose(const float* __restrict__ x, unsigned short* __restrict__ Vt) {
    __shared__ __attribute__((aligned(16))) unsigned short T[64 * 66];
    unsigned* T32 = reinterpret_cast<unsigned*>(T);

    const int tid = threadIdx.x;
    const int bh = blockIdx.y;
    const int b = bh >> 3, h = bh & 7;
    const int n0 = blockIdx.x * 64;

#pragma unroll
    for (int j = 0; j < 2; ++j) {
        int cid = tid + 256 * j;
        int ni = cid >> 3;
        int d0 = (cid & 7) * 8;
        const float* src = x + (size_t)2 * CSTRIDE +
            ((size_t)(b * 4096 + n0 + ni)) * 512 + h * 64 + d0;
        float4 a0 = *reinterpret_cast<const float4*>(src);
        float4 a1 = *reinterpret_cast<const float4*>(src + 4);
        short8 v = cvt8(a0, a1);
#pragma unroll
        for (int k = 0; k < 4; ++k) {
            unsigned pk = (unsigned)(unsigned short)v[2 * k] |
                          ((unsigned)(unsigned short)v[2 * k + 1] << 16);
            T32[ni * 33 + (d0 >> 1) + k] = pk;
        }
    }
    __syncthreads();

#pragma unroll
    for (int j = 0; j < 2; ++j) {
        int cid = tid + 256 * j;
        int di = cid >> 3;
        int k0 = (cid & 7) * 8;
        short8 o;
#pragma unroll
        for (int k = 0; k < 8; ++k) o[k] = (short)T[(k0 + k) * 66 + di];
        unsigned short* dst = Vt + ((size_t)(bh * 64 + di)) * 4096 + n0 + k0;
        *reinterpret_cast<short8*>(dst) = o;
    }
}

// ---------------------------------------------------------------------------
// Prepass 3: W fp32 [512,512] -> bf16
// ---------------------------------------------------------------------------
__global__ __launch_bounds__(256)
void w_convert(const float* __restrict__ W, unsigned short* __restrict__ Wbf) {
    int cid = blockIdx.x * 256 + threadIdx.x;
    int d8 = cid & 63;
    int row = cid >> 6;
    const float* src = W + (size_t)row * 512 + d8 * 8;
    float4 a0 = *reinterpret_cast<const float4*>(src);
    float4 a1 = *reinterpret_cast<const float4*>(src + 4);
    *reinterpret_cast<short8*>(Wbf + (size_t)row * 512 + d8 * 8) = cvt8(a0, a1);
}

// ---------------------------------------------------------------------------
// Flash attention, 32x32x16 MFMA: 8-wave blocks = 4 q-subtiles (32q) x
// 2 KV-halves; async gload_lds double-buffer, ONE barrier per 64-key step.
// grid (32 q-tiles of 128, 16 b*h) = 512 blocks x 8 waves (512 thr)
//   wave w: half = w>>2 (keys half*2048..+2048), p = w&3 (32 q-rows).
// -> 2 blocks/CU, 16 waves/CU, 4 waves/SIMD (launch_bounds(512,4), VGPR<=128).
// Q read directly from x (scaled+cvt in-kernel, once per block).
// End: in-LDS fp32 add-combine (aliases staging; no DMA in flight there).
// No max tracking (log2-unit scores, |S| <= ~10; fp32 margin ~2^100).
// ---------------------------------------------------------------------------
#define SMEM_BYTES 65536  // 2 halves x 2 bufs x (K 8K + V 8K); combine aliases

__global__ __launch_bounds__(512, 4)
void attn_kernel(const float* __restrict__ x,
                 const unsigned short* __restrict__ Kbf,
                 const unsigned short* __restrict__ Vt,
                 unsigned short* __restrict__ Obf) {
    __shared__ __attribute__((aligned(16))) unsigned char SMEM[SMEM_BYTES];

    const int tid = threadIdx.x;
    const int lane = tid & 63;
    const int wv = tid >> 6;    // 0..7
    const int hi = lane >> 5;
    const int l5 = lane & 31;
    const int half = wv >> 2;   // KV half
    const int p = wv & 3;       // q-subtile (32 rows)

    const int bh = blockIdx.y;
    const int b = bh >> 3, h = bh & 7;
    const int qbase = blockIdx.x * 128 + p * 32;

    const unsigned short* Kh = Kbf + (size_t)bh * NSEQ * HD;
    const unsigned short* Vh = Vt + (size_t)bh * HD * NSEQ;

    char* K_base = (char*)SMEM + half * 32768;  // [buf0: K 8K | V 8K][buf1: ...]

    // Q fragments from x (channel 0), scaled: lane holds Q[q=l5][d=c*16+hi*8+j]
    short8 qf[4];
#pragma unroll
    for (int c = 0; c < 4; ++c) {
        const float* qp = x + ((size_t)(b * 4096 + qbase + l5)) * 512 + h * 64 + c * 16 + hi * 8;
        float4 a0 = *reinterpret_cast<const float4*>(qp);
        float4 a1 = *reinterpret_cast<const float4*>(qp + 4);
        a0.x *= QSCALE; a0.y *= QSCALE; a0.z *= QSCALE; a0.w *= QSCALE;
        a1.x *= QSCALE; a1.y *= QSCALE; a1.z *= QSCALE; a1.w *= QSCALE;
        qf[c] = cvt8(a0, a1);
    }

    f32x16 zero16;
#pragma unroll
    for (int r = 0; r < 16; ++r) zero16[r] = 0.f;

    f32x16 oacc[2];
    oacc[0] = zero16;
    oacc[1] = zero16;
    float l_run = 0.f;

    const int kt0 = half * 32;
    const int swz = (l5 & 7) << 4;

    // pre-swizzled source addressing for linear gload_lds dest:
    // chunk j (0..7), lane l: LDS byte L = j*1024 + l*16 ->
    //   row = j*8 + (l>>3); elem e = ((l&7)*8) ^ ((l>>3)*8)
    const int lrow = lane >> 3;                       // 0..7
    const int lelem = ((lane & 7) * 8) ^ (lrow * 8);  // pre-swizzled elem offset
    const int j0 = p * 2;                             // this wave's 2 chunks

    // prologue: issue tile kt0 -> buf 0 (each wave: 2 K-chunks + 2 V-chunks)
    {
        char* Kb = K_base;
        char* Vb = K_base + 8192;
#pragma unroll
        for (int i = 0; i < 2; ++i) {
            int j = j0 + i;
            int row = j * 8 + lrow;
            gload_lds16(Kh + (size_t)(kt0 * 64 + row) * HD + lelem, Kb + j * 1024);
            gload_lds16(Vh + (size_t)row * NSEQ + kt0 * 64 + lelem, Vb + j * 1024);
        }
    }
    __syncthreads();  // implicit vmcnt(0) drain: buf0 ready

    int cur = 0;
    for (int step = 0; step < 32; ++step) {
        // issue async loads for tile step+1 into buf[cur^1] (free since the
        // barrier ending step-1). Skip at step 31 (combine aliases LDS).
        if (step < 31) {
            int nt = kt0 + step + 1;
            char* Kb = K_base + (cur ^ 1) * 16384;
            char* Vb = Kb + 8192;
#pragma unroll
            for (int i = 0; i < 2; ++i) {
                int j = j0 + i;
                int row = j * 8 + lrow;
                gload_lds16(Kh + (size_t)(nt * 64 + row) * HD + lelem, Kb + j * 1024);
                gload_lds16(Vh + (size_t)row * NSEQ + nt * 64 + lelem, Vb + j * 1024);
            }
        }

        const char* K_lds = K_base + cur * 16384;
        const char* V_lds = K_lds + 8192;

        // ---- S^T = K Q^T : lane holds S[key = kb*32+(r&3)+8*(r>>2)+4*hi][q=l5]
        f32x16 st[2];
        __builtin_amdgcn_s_setprio(1);
#pragma unroll
        for (int kb = 0; kb < 2; ++kb) {
            int key = kb * 32 + l5;
            short8 kf0 = *reinterpret_cast<const short8*>(
                K_lds + ((key * 128 + 0 * 32 + hi * 16) ^ swz));
            f32x16 a = MFMA32(kf0, qf[0], zero16);
#pragma unroll
            for (int c = 1; c < 4; ++c) {
                short8 kf = *reinterpret_cast<const short8*>(
                    K_lds + ((key * 128 + c * 32 + hi * 16) ^ swz));
                a = MFMA32(kf, qf[c], a);
            }
            st[kb] = a;
        }
        __builtin_amdgcn_s_setprio(0);

        // ---- p = exp2(S); l row-sum on VALU ----
#pragma unroll
        for (int kb = 0; kb < 2; ++kb)
#pragma unroll
            for (int r = 0; r < 16; ++r)
                st[kb][r] = __builtin_amdgcn_exp2f(st[kb][r]);
        {
            float s = 0.f;
#pragma unroll
            for (int r = 0; r < 16; ++r) s += st[0][r] + st[1][r];
            s += __shfl_xor(s, 32);  // add other half-wave's 32 keys
            l_run += s;              // lane l holds l for q = (l&31)
        }

        // ---- P^T -> PV A-fragments, in-register (cvt_pk + shfl_xor + select) ----
        short8 PA[4];
#pragma unroll
        for (int kb = 0; kb < 2; ++kb)
#pragma unroll
            for (int ks = 0; ks < 2; ++ks) {
                unsigned c0 = cvt_pk_bf16(st[kb][8 * ks + 0], st[kb][8 * ks + 1]);
                unsigned c1 = cvt_pk_bf16(st[kb][8 * ks + 2], st[kb][8 * ks + 3]);
                unsigned c2 = cvt_pk_bf16(st[kb][8 * ks + 4], st[kb][8 * ks + 5]);
                unsigned c3 = cvt_pk_bf16(st[kb][8 * ks + 6], st[kb][8 * ks + 7]);
                unsigned d0 = (unsigned)__shfl_xor((int)c0, 32);
                unsigned d1 = (unsigned)__shfl_xor((int)c1, 32);
                unsigned d2 = (unsigned)__shfl_xor((int)c2, 32);
                unsigned d3 = (unsigned)__shfl_xor((int)c3, 32);
                uint4v w;
                w[0] = hi ? d2 : c0;
                w[1] = hi ? d3 : c1;
                w[2] = hi ? c2 : d0;
                w[3] = hi ? c3 : d1;
                PA[kb * 2 + ks] = __builtin_bit_cast(short8, w);
            }

        // ---- PV ----
        __builtin_amdgcn_s_setprio(1);
#pragma unroll
        for (int ch = 0; ch < 4; ++ch) {
#pragma unroll
            for (int db = 0; db < 2; ++db) {
                int d = db * 32 + l5;
                short8 vf = *reinterpret_cast<const short8*>(
                    V_lds + ((d * 128 + ch * 32 + hi * 16) ^ swz));
                oacc[db] = MFMA32(PA[ch], vf, oacc[db]);
            }
        }
        __builtin_amdgcn_s_setprio(0);

        __syncthreads();  // drains this wave's DMA (vmcnt) + LDS reads; swap
        cur ^= 1;
    }

    // ---- in-LDS fp32 add-combine: half 1 -> Xo/Xl; half 0 merges + writes ----
    float* Xo = (float*)SMEM;             // [128 q][64 d] fp32 (aliases staging)
    float* Xl = (float*)(SMEM + 32768);   // [128]

    if (half == 1) {
#pragma unroll
        for (int r = 0; r < 16; ++r) {
            int crow = (r & 3) + 8 * (r >> 2) + 4 * hi;
            int qloc = p * 32 + crow;
            Xo[qloc * 64 + l5] = oacc[0][r];
            Xo[qloc * 64 + 32 + l5] = oacc[1][r];
        }
        if (hi == 0) Xl[p * 32 + l5] = l_run;
    }
    __syncthreads();
    if (half == 0) {
#pragma unroll
        for (int r = 0; r < 16; ++r) {
            int crow = (r & 3) + 8 * (r >> 2) + 4 * hi;
            int qloc = p * 32 + crow;
            float l1 = Xl[qloc];
            float inv = 1.0f / (__shfl(l_run, crow) + l1);
            float v0 = oacc[0][r] + Xo[qloc * 64 + l5];
            float v1 = oacc[1][r] + Xo[qloc * 64 + 32 + l5];
            int qrow = qbase + crow;
            size_t obase = (size_t)(b * NSEQ + qrow) * DMODEL + h * HD;
            Obf[obase + l5] = f2bf(v0 * inv);
            Obf[obase + 32 + l5] = f2bf(v1 * inv);
        }
    }
}

// ---------------------------------------------------------------------------
// Projection: Y[8192,512] = O_bf16 @ Wbf^T + bias
// ---------------------------------------------------------------------------
__global__ __launch_bounds__(256, 4)
void proj_kernel(const unsigned short* __restrict__ Obf, const unsigned short* __restrict__ Wbf,
                 const float* __restrict__ bias, float* __restrict__ out) {
    __shared__ __attribute__((aligned(16))) unsigned short W_lds[64 * 64];  // [j][k] swz

    const int tid = threadIdx.x;
    const int lane = tid & 63;
    const int wv = tid >> 6;
    const int g = lane >> 4;
    const int l4 = lane & 15;

    const int bm = blockIdx.x;
    const int bn = blockIdx.y;

    f32x4 acc[4];
#pragma unroll
    for (int jt = 0; jt < 4; ++jt) acc[jt] = (f32x4){0.f, 0.f, 0.f, 0.f};

    for (int kc = 0; kc < DMODEL / 64; ++kc) {
#pragma unroll
        for (int j = 0; j < 2; ++j) {
            int cid = tid + 256 * j;
            int row = cid >> 3;
            int ee = (cid & 7) * 8;
            short8 wv8 = *reinterpret_cast<const short8*>(
                Wbf + (size_t)(bn * 64 + row) * DMODEL + kc * 64 + ee);
            int off = (row * 128 + ee * 2) ^ ((row & 7) << 4);
            *reinterpret_cast<short8*>((char*)W_lds + off) = wv8;
        }
        __syncthreads();

#pragma unroll
        for (int sub = 0; sub < 2; ++sub) {
            const unsigned short* ap =
                Obf + (size_t)(bm * 64 + wv * 16 + l4) * DMODEL + kc * 64 + sub * 32 + g * 8;
            short8 a = *reinterpret_cast<const short8*>(ap);
#pragma unroll
            for (int jt = 0; jt < 4; ++jt) {
                int jj = jt * 16 + l4;
                int off = (jj * 128 + (sub * 32 + g * 8) * 2) ^ ((jj & 7) << 4);
                short8 wb = *reinterpret_cast<const short8*>((const char*)W_lds + off);
                acc[jt] = MFMA16(a, wb, acc[jt]);
            }
        }
        __syncthreads();
    }

#pragma unroll
    for (int jt = 0; jt < 4; ++jt) {
        int jg = bn * 64 + jt * 16 + l4;
        float bj = bias[jg];
#pragma unroll
        for (int r = 0; r < 4; ++r) {
            int ig = bm * 64 + wv * 16 + g * 4 + r;
            out[(size_t)ig * DMODEL + jg] = acc[jt][r] + bj;
        }
    }
}

extern "C" void kernel_launch(void* const* d_in, const int* in_sizes, int n_in,
                              void* d_out, int out_size, void* d_ws, size_t ws_size,
                              hipStream_t stream) {
    const float* x = (const float*)d_in[0];     // [3, 2, 4096, 512] fp32
    const float* W = (const float*)d_in[1];     // [512, 512] fp32
    const float* bias = (const float*)d_in[2];  // [512] fp32
    float* out = (float*)d_out;                 // [2, 4096, 512] fp32

    // workspace layout (24.5 MB, within the proven 32.5 MB footprint):
    char* ws = (char*)d_ws;
    unsigned short* Obf = (unsigned short*)(ws);                // [0, 8MB)
    unsigned short* Kbf = (unsigned short*)(ws + (8u << 20));   // [8, 16)
    unsigned short* Vt = (unsigned short*)(ws + (16u << 20));   // [16, 24)
    unsigned short* Wbf = (unsigned short*)(ws + (24u << 20));  // [24, 24.5)

    k_convert<<<2048, 256, 0, stream>>>(x, Kbf);
    v_transpose<<<dim3(NSEQ / 64, NB * NH), 256, 0, stream>>>(x, Vt);
    w_convert<<<128, 256, 0, stream>>>(W, Wbf);

    dim3 gA(NSEQ / 128, NB * NH);  // (32, 16) = 512 blocks x 8 waves
    attn_kernel<<<gA, 512, 0, stream>>>(x, Kbf, Vt, Obf);

    dim3 gP(NB * NSEQ / 64, DMODEL / 64);  // (128, 8)
    proj_kernel<<<gP, 256, 0, stream>>>(Obf, Wbf, bias, out);
}